// Round 1
// baseline (2811.291 us; speedup 1.0000x reference)
//
#include <hip/hip_runtime.h>

// GraphGCN: out = (x + mean_agg(x)) * 0.5 where x = mean_agg(features)
// features: [N,64] f32, src/dst: [E] int (harness delivers integer inputs as int32)
//
// Pipeline (all on `stream`):
//   memset deg, buf_x, d_out
//   deg[dst[e]] += 1                          (int atomics)
//   buf_x[dst[e]*64+j] += feat[src[e]*64+j]   (fp32 HW atomics)
//   buf_x[n] *= 1/max(deg[n],1)               (now buf_x == x)
//   d_out[dst[e]*64+j] += buf_x[src[e]*64+j]  (sum2)
//   d_out[n] = (buf_x[n] + d_out[n]*inv) * 0.5

__global__ void deg_kernel(const int* __restrict__ dst, int E, int* __restrict__ deg) {
    int stride = gridDim.x * blockDim.x;
    for (int e = blockIdx.x * blockDim.x + threadIdx.x; e < E; e += stride) {
        atomicAdd(&deg[dst[e]], 1);
    }
}

// Each edge handled by 16 consecutive lanes; lane c covers floats [c*4, c*4+4).
// A 64-lane wave therefore processes 4 edges; the 256B row gather is coalesced.
__global__ void scatter_kernel(const float* __restrict__ feat,
                               const int* __restrict__ src,
                               const int* __restrict__ dst,
                               int E, float* __restrict__ sum) {
    int total = E * 16;  // 25.6M < 2^31
    int stride = gridDim.x * blockDim.x;
    for (int t = blockIdx.x * blockDim.x + threadIdx.x; t < total; t += stride) {
        int e = t >> 4;
        int c = t & 15;
        int s = src[e];
        int d = dst[e];
        const float4 v = *reinterpret_cast<const float4*>(feat + (size_t)s * 64 + c * 4);
        float* o = sum + (size_t)d * 64 + c * 4;
        unsafeAtomicAdd(o + 0, v.x);
        unsafeAtomicAdd(o + 1, v.y);
        unsafeAtomicAdd(o + 2, v.z);
        unsafeAtomicAdd(o + 3, v.w);
    }
}

__global__ void normalize_kernel(float* __restrict__ x, const int* __restrict__ deg, int N) {
    int total = N * 16;
    int stride = gridDim.x * blockDim.x;
    for (int t = blockIdx.x * blockDim.x + threadIdx.x; t < total; t += stride) {
        int n = t >> 4;
        int c = t & 15;
        float inv = 1.0f / fmaxf((float)deg[n], 1.0f);
        float4* p = reinterpret_cast<float4*>(x + (size_t)n * 64 + c * 4);
        float4 v = *p;
        v.x *= inv; v.y *= inv; v.z *= inv; v.w *= inv;
        *p = v;
    }
}

// out currently holds sum2; x holds normalized first-hop means.
// out = (x + sum2 * inv) * 0.5
__global__ void final_kernel(const float* __restrict__ x, const int* __restrict__ deg,
                             float* __restrict__ out, int N) {
    int total = N * 16;
    int stride = gridDim.x * blockDim.x;
    for (int t = blockIdx.x * blockDim.x + threadIdx.x; t < total; t += stride) {
        int n = t >> 4;
        int c = t & 15;
        float inv = 1.0f / fmaxf((float)deg[n], 1.0f);
        const float4 xv = *reinterpret_cast<const float4*>(x + (size_t)n * 64 + c * 4);
        float4* op = reinterpret_cast<float4*>(out + (size_t)n * 64 + c * 4);
        float4 s2 = *op;
        float4 r;
        r.x = (xv.x + s2.x * inv) * 0.5f;
        r.y = (xv.y + s2.y * inv) * 0.5f;
        r.z = (xv.z + s2.z * inv) * 0.5f;
        r.w = (xv.w + s2.w * inv) * 0.5f;
        *op = r;
    }
}

extern "C" void kernel_launch(void* const* d_in, const int* in_sizes, int n_in,
                              void* d_out, int out_size, void* d_ws, size_t ws_size,
                              hipStream_t stream) {
    const float* feat = (const float*)d_in[0];
    const int*   src  = (const int*)d_in[1];
    const int*   dst  = (const int*)d_in[2];
    float* out = (float*)d_out;

    const int D = 64;
    int N = in_sizes[0] / D;   // 100000
    int E = in_sizes[1];       // 1600000

    float* buf_x = (float*)d_ws;                                   // N*64 floats
    int*   deg   = (int*)((char*)d_ws + (size_t)N * D * sizeof(float)); // N ints

    hipMemsetAsync(buf_x, 0, (size_t)N * D * sizeof(float), stream);
    hipMemsetAsync(deg, 0, (size_t)N * sizeof(int), stream);
    hipMemsetAsync(out, 0, (size_t)N * D * sizeof(float), stream);

    const int BLK = 256;
    int grid_e  = min((E + BLK - 1) / BLK, 2048);
    int grid_s  = 4096;   // 1.05M threads grid-striding over E*16 = 25.6M items
    int grid_n  = min((N * 16 + BLK - 1) / BLK, 2048);

    deg_kernel<<<grid_e, BLK, 0, stream>>>(dst, E, deg);
    scatter_kernel<<<grid_s, BLK, 0, stream>>>(feat, src, dst, E, buf_x);
    normalize_kernel<<<grid_n, BLK, 0, stream>>>(buf_x, deg, N);
    scatter_kernel<<<grid_s, BLK, 0, stream>>>(buf_x, src, dst, E, out);
    final_kernel<<<grid_n, BLK, 0, stream>>>(buf_x, deg, out, N);
}

// Round 2
// 322.732 us; speedup vs baseline: 8.7109x; 8.7109x over previous
//
#include <hip/hip_runtime.h>

// GraphGCN via CSR-by-dst + gather aggregation (no fp32 atomics).
//   deg[n]       = in-degree histogram
//   offs[0..N]   = exclusive prefix sum of deg
//   edge_src[]   = src ids bucketed by dst (counting sort via cursor atomics)
//   agg pass1: buf_x[n] = mean_{e: dst=n} feat[src[e]]            (write-once rows)
//   agg pass2: out[n]   = (buf_x[n] + mean_{e: dst=n} buf_x[src[e]]) * 0.5

#define SCAN_CHUNK 2048   // 256 threads x 8 elements

__global__ void deg_kernel(const int* __restrict__ dst, int E, int* __restrict__ deg) {
    int stride = gridDim.x * blockDim.x;
    for (int e = blockIdx.x * blockDim.x + threadIdx.x; e < E; e += stride)
        atomicAdd(&deg[dst[e]], 1);
}

__global__ void scan_chunks(const int* __restrict__ deg, int N,
                            int* __restrict__ offs, int* __restrict__ blockSums) {
    __shared__ int lds[256];
    int b = blockIdx.x;
    int tid = threadIdx.x;
    int idx0 = b * SCAN_CHUNK + tid * 8;
    int v[8];
    int sum = 0;
#pragma unroll
    for (int i = 0; i < 8; ++i) {
        int idx = idx0 + i;
        int d = (idx < N) ? deg[idx] : 0;
        v[i] = d; sum += d;
    }
    lds[tid] = sum;
    __syncthreads();
    for (int s = 1; s < 256; s <<= 1) {
        int t = (tid >= s) ? lds[tid - s] : 0;
        __syncthreads();
        lds[tid] += t;
        __syncthreads();
    }
    int run = (tid == 0) ? 0 : lds[tid - 1];
    if (tid == 255) blockSums[b] = lds[255];
#pragma unroll
    for (int i = 0; i < 8; ++i) {
        int idx = idx0 + i;
        if (idx < N) offs[idx] = run;
        run += v[i];
    }
}

__global__ void scan_blocksums(int* __restrict__ blockSums, int nb,
                               int* __restrict__ offs, int N) {
    if (blockIdx.x == 0 && threadIdx.x == 0) {
        int run = 0;
        for (int b = 0; b < nb; ++b) { int t = blockSums[b]; blockSums[b] = run; run += t; }
        offs[N] = run;
    }
}

__global__ void add_offsets(int* __restrict__ offs, int* __restrict__ cursor,
                            const int* __restrict__ blockSums, int N) {
    int i = blockIdx.x * blockDim.x + threadIdx.x;
    if (i < N) {
        int o = offs[i] + blockSums[i / SCAN_CHUNK];
        offs[i] = o;
        cursor[i] = o;
    }
}

__global__ void fill_kernel(const int* __restrict__ src, const int* __restrict__ dst,
                            int E, int* __restrict__ cursor, int* __restrict__ edge_src) {
    int stride = gridDim.x * blockDim.x;
    for (int e = blockIdx.x * blockDim.x + threadIdx.x; e < E; e += stride) {
        int pos = atomicAdd(&cursor[dst[e]], 1);
        edge_src[pos] = src[e];
    }
}

// One node row per 16 consecutive lanes; lane c owns float4 chunk c.
// FINAL=0: out = acc*inv (normalized mean).  FINAL=1: out = (xskip + acc*inv)*0.5.
template <int FINAL>
__global__ void agg_kernel(const float* __restrict__ xin,
                           const int* __restrict__ offs,
                           const int* __restrict__ edge_src,
                           const float* __restrict__ xskip,
                           float* __restrict__ outbuf, int N) {
    int t = blockIdx.x * blockDim.x + threadIdx.x;
    int n = t >> 4;
    int c = t & 15;
    if (n >= N) return;
    int beg = offs[n];
    int end = offs[n + 1];
    float ax = 0.f, ay = 0.f, az = 0.f, aw = 0.f;
    int k = beg;
    for (; k + 4 <= end; k += 4) {
        int s0 = edge_src[k + 0];
        int s1 = edge_src[k + 1];
        int s2 = edge_src[k + 2];
        int s3 = edge_src[k + 3];
        const float4 v0 = *reinterpret_cast<const float4*>(xin + (size_t)s0 * 64 + c * 4);
        const float4 v1 = *reinterpret_cast<const float4*>(xin + (size_t)s1 * 64 + c * 4);
        const float4 v2 = *reinterpret_cast<const float4*>(xin + (size_t)s2 * 64 + c * 4);
        const float4 v3 = *reinterpret_cast<const float4*>(xin + (size_t)s3 * 64 + c * 4);
        ax += v0.x + v1.x + v2.x + v3.x;
        ay += v0.y + v1.y + v2.y + v3.y;
        az += v0.z + v1.z + v2.z + v3.z;
        aw += v0.w + v1.w + v2.w + v3.w;
    }
    for (; k < end; ++k) {
        int s = edge_src[k];
        const float4 v = *reinterpret_cast<const float4*>(xin + (size_t)s * 64 + c * 4);
        ax += v.x; ay += v.y; az += v.z; aw += v.w;
    }
    float inv = (end > beg) ? 1.0f / (float)(end - beg) : 0.0f;
    float4 r;
    if (FINAL) {
        const float4 xs = *reinterpret_cast<const float4*>(xskip + (size_t)n * 64 + c * 4);
        r.x = (xs.x + ax * inv) * 0.5f;
        r.y = (xs.y + ay * inv) * 0.5f;
        r.z = (xs.z + az * inv) * 0.5f;
        r.w = (xs.w + aw * inv) * 0.5f;
    } else {
        r.x = ax * inv;
        r.y = ay * inv;
        r.z = az * inv;
        r.w = aw * inv;
    }
    *reinterpret_cast<float4*>(outbuf + (size_t)n * 64 + c * 4) = r;
}

static inline size_t align_up(size_t x, size_t a) { return (x + a - 1) & ~(a - 1); }

extern "C" void kernel_launch(void* const* d_in, const int* in_sizes, int n_in,
                              void* d_out, int out_size, void* d_ws, size_t ws_size,
                              hipStream_t stream) {
    const float* feat = (const float*)d_in[0];
    const int*   src  = (const int*)d_in[1];
    const int*   dst  = (const int*)d_in[2];
    float* out = (float*)d_out;

    const int D = 64;
    int N = in_sizes[0] / D;   // 100000
    int E = in_sizes[1];       // 1600000
    int NB = (N + SCAN_CHUNK - 1) / SCAN_CHUNK;  // 49

    // workspace layout
    char* ws = (char*)d_ws;
    size_t off = 0;
    float* buf_x = (float*)(ws + off); off = align_up(off + (size_t)N * D * sizeof(float), 256);
    int* deg     = (int*)(ws + off);   off = align_up(off + (size_t)N * sizeof(int), 256);
    int* offs    = (int*)(ws + off);   off = align_up(off + (size_t)(N + 1) * sizeof(int), 256);
    int* cursor  = (int*)(ws + off);   off = align_up(off + (size_t)N * sizeof(int), 256);
    int* bsums   = (int*)(ws + off);   off = align_up(off + (size_t)NB * sizeof(int), 256);
    int* edge_src= (int*)(ws + off);   off = align_up(off + (size_t)E * sizeof(int), 256);
    (void)ws_size;

    hipMemsetAsync(deg, 0, (size_t)N * sizeof(int), stream);

    const int BLK = 256;
    int grid_e = min((E + BLK - 1) / BLK, 2048);
    int grid_n = (N + BLK - 1) / BLK;
    int grid_a = (N * 16 + BLK - 1) / BLK;

    deg_kernel<<<grid_e, BLK, 0, stream>>>(dst, E, deg);
    scan_chunks<<<NB, BLK, 0, stream>>>(deg, N, offs, bsums);
    scan_blocksums<<<1, 64, 0, stream>>>(bsums, NB, offs, N);
    add_offsets<<<grid_n, BLK, 0, stream>>>(offs, cursor, bsums, N);
    fill_kernel<<<grid_e, BLK, 0, stream>>>(src, dst, E, cursor, edge_src);

    agg_kernel<0><<<grid_a, BLK, 0, stream>>>(feat, offs, edge_src, nullptr, buf_x, N);
    agg_kernel<1><<<grid_a, BLK, 0, stream>>>(buf_x, offs, edge_src, buf_x, out, N);
}

// Round 3
// 275.717 us; speedup vs baseline: 10.1963x; 1.1705x over previous
//
#include <hip/hip_runtime.h>

// GraphGCN via CSR-by-dst + gather aggregation (no fp32 atomics).
// R2: XCD-partitioned histogram/fill — node range = blockIdx&7 so each XCD's
// L2 owns one 1/8 slice of deg/cursor/edge_src; scattered 4B stores now merge
// in that XCD's L2 instead of causing ~64B/store HBM writebacks (R1: 107MB
// WRITE_SIZE for a 6.4MB array).

#define SCAN_CHUNK 2048   // 256 threads x 8 elements

// Partitioned histogram: part p handles nodes [p*np, (p+1)*np).
__global__ void deg_kernel(const int* __restrict__ dst, int E, int N,
                           int* __restrict__ deg) {
    int part = blockIdx.x & 7;
    int np = (N + 7) >> 3;
    int lo = part * np;
    int hi = min(N, lo + np);
    int nchunks = gridDim.x >> 3;
    int chunk = blockIdx.x >> 3;
    int per = (E + nchunks - 1) / nchunks;
    int beg = chunk * per;
    int end = min(E, beg + per);
    for (int e = beg + threadIdx.x; e < end; e += blockDim.x) {
        int d = dst[e];
        if (d >= lo && d < hi) atomicAdd(&deg[d], 1);
    }
}

__global__ void scan_chunks(const int* __restrict__ deg, int N,
                            int* __restrict__ offs, int* __restrict__ blockSums) {
    __shared__ int lds[256];
    int b = blockIdx.x;
    int tid = threadIdx.x;
    int idx0 = b * SCAN_CHUNK + tid * 8;
    int v[8];
    int sum = 0;
#pragma unroll
    for (int i = 0; i < 8; ++i) {
        int idx = idx0 + i;
        int d = (idx < N) ? deg[idx] : 0;
        v[i] = d; sum += d;
    }
    lds[tid] = sum;
    __syncthreads();
    for (int s = 1; s < 256; s <<= 1) {
        int t = (tid >= s) ? lds[tid - s] : 0;
        __syncthreads();
        lds[tid] += t;
        __syncthreads();
    }
    int run = (tid == 0) ? 0 : lds[tid - 1];
    if (tid == 255) blockSums[b] = lds[255];
#pragma unroll
    for (int i = 0; i < 8; ++i) {
        int idx = idx0 + i;
        if (idx < N) offs[idx] = run;
        run += v[i];
    }
}

__global__ void scan_blocksums(int* __restrict__ blockSums, int nb,
                               int* __restrict__ offs, int N) {
    if (blockIdx.x == 0 && threadIdx.x == 0) {
        int run = 0;
        for (int b = 0; b < nb; ++b) { int t = blockSums[b]; blockSums[b] = run; run += t; }
        offs[N] = run;
    }
}

__global__ void add_offsets(int* __restrict__ offs, int* __restrict__ cursor,
                            const int* __restrict__ blockSums, int N) {
    int i = blockIdx.x * blockDim.x + threadIdx.x;
    if (i < N) {
        int o = offs[i] + blockSums[i / SCAN_CHUNK];
        offs[i] = o;
        cursor[i] = o;
    }
}

// Partitioned bucket fill: same node-range scheme as deg_kernel, so cursor
// atomics and edge_src stores for one slice all come from one XCD.
__global__ void fill_kernel(const int* __restrict__ src, const int* __restrict__ dst,
                            int E, int N,
                            int* __restrict__ cursor, int* __restrict__ edge_src) {
    int part = blockIdx.x & 7;
    int np = (N + 7) >> 3;
    int lo = part * np;
    int hi = min(N, lo + np);
    int nchunks = gridDim.x >> 3;
    int chunk = blockIdx.x >> 3;
    int per = (E + nchunks - 1) / nchunks;
    int beg = chunk * per;
    int end = min(E, beg + per);
    for (int e = beg + threadIdx.x; e < end; e += blockDim.x) {
        int d = dst[e];
        if (d >= lo && d < hi) {
            int pos = atomicAdd(&cursor[d], 1);
            edge_src[pos] = src[e];
        }
    }
}

// One node row per 16 consecutive lanes; lane c owns float4 chunk c.
// FINAL=0: out = acc*inv (normalized mean).  FINAL=1: out = (xskip + acc*inv)*0.5.
template <int FINAL>
__launch_bounds__(256)
__global__ void agg_kernel(const float* __restrict__ xin,
                           const int* __restrict__ offs,
                           const int* __restrict__ edge_src,
                           const float* __restrict__ xskip,
                           float* __restrict__ outbuf, int N) {
    int t = blockIdx.x * blockDim.x + threadIdx.x;
    int n = t >> 4;
    int c = t & 15;
    if (n >= N) return;
    int beg = offs[n];
    int end = offs[n + 1];
    float ax = 0.f, ay = 0.f, az = 0.f, aw = 0.f;
    int k = beg;
    for (; k + 8 <= end; k += 8) {
        int s[8];
#pragma unroll
        for (int i = 0; i < 8; ++i) s[i] = edge_src[k + i];
#pragma unroll
        for (int i = 0; i < 8; ++i) {
            const float4 v = *reinterpret_cast<const float4*>(xin + ((size_t)s[i] << 6) + c * 4);
            ax += v.x; ay += v.y; az += v.z; aw += v.w;
        }
    }
    for (; k < end; ++k) {
        int s = edge_src[k];
        const float4 v = *reinterpret_cast<const float4*>(xin + ((size_t)s << 6) + c * 4);
        ax += v.x; ay += v.y; az += v.z; aw += v.w;
    }
    float inv = (end > beg) ? 1.0f / (float)(end - beg) : 0.0f;
    float4 r;
    if (FINAL) {
        const float4 xs = *reinterpret_cast<const float4*>(xskip + ((size_t)n << 6) + c * 4);
        r.x = (xs.x + ax * inv) * 0.5f;
        r.y = (xs.y + ay * inv) * 0.5f;
        r.z = (xs.z + az * inv) * 0.5f;
        r.w = (xs.w + aw * inv) * 0.5f;
    } else {
        r.x = ax * inv;
        r.y = ay * inv;
        r.z = az * inv;
        r.w = aw * inv;
    }
    *reinterpret_cast<float4*>(outbuf + ((size_t)n << 6) + c * 4) = r;
}

static inline size_t align_up(size_t x, size_t a) { return (x + a - 1) & ~(a - 1); }

extern "C" void kernel_launch(void* const* d_in, const int* in_sizes, int n_in,
                              void* d_out, int out_size, void* d_ws, size_t ws_size,
                              hipStream_t stream) {
    const float* feat = (const float*)d_in[0];
    const int*   src  = (const int*)d_in[1];
    const int*   dst  = (const int*)d_in[2];
    float* out = (float*)d_out;

    const int D = 64;
    int N = in_sizes[0] / D;   // 100000
    int E = in_sizes[1];       // 1600000
    int NB = (N + SCAN_CHUNK - 1) / SCAN_CHUNK;  // 49

    // workspace layout
    char* ws = (char*)d_ws;
    size_t off = 0;
    float* buf_x = (float*)(ws + off); off = align_up(off + (size_t)N * D * sizeof(float), 256);
    int* deg     = (int*)(ws + off);   off = align_up(off + (size_t)N * sizeof(int), 256);
    int* offs    = (int*)(ws + off);   off = align_up(off + (size_t)(N + 1) * sizeof(int), 256);
    int* cursor  = (int*)(ws + off);   off = align_up(off + (size_t)N * sizeof(int), 256);
    int* bsums   = (int*)(ws + off);   off = align_up(off + (size_t)NB * sizeof(int), 256);
    int* edge_src= (int*)(ws + off);   off = align_up(off + (size_t)E * sizeof(int), 256);
    (void)ws_size;

    hipMemsetAsync(deg, 0, (size_t)N * sizeof(int), stream);

    const int BLK = 256;
    int grid_part = 2048;  // 256 chunks x 8 XCD parts
    int grid_n = (N + BLK - 1) / BLK;
    int grid_a = (N * 16 + BLK - 1) / BLK;

    deg_kernel<<<grid_part, BLK, 0, stream>>>(dst, E, N, deg);
    scan_chunks<<<NB, BLK, 0, stream>>>(deg, N, offs, bsums);
    scan_blocksums<<<1, 64, 0, stream>>>(bsums, NB, offs, N);
    add_offsets<<<grid_n, BLK, 0, stream>>>(offs, cursor, bsums, N);
    fill_kernel<<<grid_part, BLK, 0, stream>>>(src, dst, E, N, cursor, edge_src);

    agg_kernel<0><<<grid_a, BLK, 0, stream>>>(feat, offs, edge_src, nullptr, buf_x, N);
    agg_kernel<1><<<grid_a, BLK, 0, stream>>>(buf_x, offs, edge_src, buf_x, out, N);
}